// Round 11
// baseline (137.380 us; speedup 1.0000x reference)
//
#include <hip/hip_runtime.h>

typedef unsigned short u16;
typedef short bf16x8 __attribute__((ext_vector_type(8)));
typedef float f32x4 __attribute__((ext_vector_type(4)));
typedef u16 u16x4 __attribute__((ext_vector_type(4)));

__device__ __forceinline__ float b2f(u16 h) {
  unsigned u = ((unsigned)h) << 16;
  return __builtin_bit_cast(float, u);
}
// native RTNE f32->bf16; compiler pairs these into v_cvt_pk_bf16_f32
__device__ __forceinline__ u16 f2b(float f) {
  return __builtin_bit_cast(u16, (__bf16)f);
}
__device__ __forceinline__ bf16x8 cvt8(f32x4 a, f32x4 b) {
  bf16x8 o;
#pragma unroll
  for (int k = 0; k < 4; k++) {
    o[k] = (short)f2b(a[k]);
    o[4 + k] = (short)f2b(b[k]);
  }
  return o;
}
__device__ __forceinline__ void gld_lds16(const void* g, void* l) {
  __builtin_amdgcn_global_load_lds(
      (__attribute__((address_space(1))) void*)(g),
      (__attribute__((address_space(3))) void*)(l), 16, 0, 0);
}

// ---------------------------------------------------------------------------
// pre2: MERGED prep+pre (replaces 2 kernels; xt round-trip eliminated).
// blocks 0-255: 8 nodes each. x cols -> in-block LDS transpose -> bf16 feat
//   -> 3-layer MFMA chain reading fp32 pre_w DIRECTLY (cvt in-register;
//   method proven in R7/R8, now on a full-GPU 256-block grid).
// blocks 256-319: post_w fp32 -> bf16 STAGED [s8(32)][m(256)][8] for main.
// ---------------------------------------------------------------------------
__global__ __launch_bounds__(256, 2) void dense_edge_pre2(
    const float* __restrict__ x, const float* __restrict__ pre_w,
    const float* __restrict__ preb, const float* __restrict__ post_w,
    u16* __restrict__ wb, u16* __restrict__ flat) {
  const int t = threadIdx.x;
  const int blk = blockIdx.x;
  if (blk >= 256) {
    const int id = (blk - 256) * 256 + t;  // 16384 slots of 8 elems
    const int layer = id >> 13;            // 0..1
    const int sid = id & 8191;
    const int m = sid >> 5;
    const int s8 = sid & 31;
    const float* src = post_w + layer * 65536;
    u16* dst = wb + layer * 65536;
    f32x4 a = *(const f32x4*)(src + m * 256 + s8 * 8);
    f32x4 c = *(const f32x4*)(src + m * 256 + s8 * 8 + 4);
    *(bf16x8*)(dst + (s8 * 256 + m) * 8) = cvt8(a, c);
    return;
  }

  __shared__ __align__(16) float tile[8 * 260];  // [hw(8)][c(260)] 8.3 KB
  __shared__ u16 feat[2][2112];  // [32 s8][8 n][8] + pad for col-overread

  const int wv = t >> 6, ln = t & 63;
  const int nb = blk * 8;
  const int b = nb >> 10, hw0 = nb & 1023;
  const int q4 = ln >> 4, r15 = ln & 15;

  // x columns: thread c reads 8 consecutive hw, scatters into [hw][c] tile
  {
    const float* src = x + (b * 256 + t) * 1024 + hw0;
    f32x4 v0 = *(const f32x4*)src;
    f32x4 v1 = *(const f32x4*)(src + 4);
#pragma unroll
    for (int e = 0; e < 4; e++) {
      tile[e * 260 + t] = v0[e];
      tile[(4 + e) * 260 + t] = v1[e];
    }
  }
  __syncthreads();
  // feat0 [s8][n][8]: thread (s8=t>>3, n=t&7) reads 8 contiguous c
  {
    const float* p = tile + (t & 7) * 260 + (t >> 3) * 8;
    f32x4 a = *(const f32x4*)p;
    f32x4 c4 = *(const f32x4*)(p + 4);
    *(bf16x8*)(&feat[0][t * 8]) = cvt8(a, c4);
  }
  __syncthreads();

  // 3-layer chain: 4 waves x 64 o-rows (mt=4); weights direct fp32 + cvt
#pragma unroll
  for (int l = 0; l < 3; l++) {
    const float* wl = pre_w + l * 65536;
    f32x4 acc[4];
    f32x4 zero = {0.f, 0.f, 0.f, 0.f};
#pragma unroll
    for (int mt = 0; mt < 4; mt++) acc[mt] = zero;
#pragma unroll
    for (int s = 0; s < 8; s++) {
      // lanes r15>=8 read junk (padded LDS) -> garbage cols, discarded
      bf16x8 bv = *(const bf16x8*)(&feat[l & 1][((s * 4 + q4) * 8 + r15) * 8]);
#pragma unroll
      for (int mt = 0; mt < 4; mt++) {
        const float* wp = wl + (wv * 64 + mt * 16 + r15) * 256 + (s * 4 + q4) * 8;
        f32x4 wa = *(const f32x4*)wp;
        f32x4 wc = *(const f32x4*)(wp + 4);
        acc[mt] = __builtin_amdgcn_mfma_f32_16x16x32_bf16(cvt8(wa, wc), bv, acc[mt], 0, 0, 0);
      }
    }
    if (l < 2) {
#pragma unroll
      for (int mt = 0; mt < 4; mt++) {
        const int o = wv * 64 + mt * 16 + q4 * 4;
        f32x4 bb = *(const f32x4*)(preb + l * 256 + o);
        u16x4 pk;
#pragma unroll
        for (int r = 0; r < 4; r++) {
          float v = fmaxf(acc[mt][r] + bb[r], 0.f);
          pk[r] = f2b(v);
        }
        if (r15 < 8)
          *(u16x4*)(&feat[(l + 1) & 1][((o >> 3) * 8 + r15) * 8 + (o & 7)]) = pk;
      }
      __syncthreads();
    } else {
#pragma unroll
      for (int mt = 0; mt < 4; mt++) {
        const int o = wv * 64 + mt * 16 + q4 * 4;
        f32x4 bb = *(const f32x4*)(preb + 512 + o);
        u16x4 pk;
#pragma unroll
        for (int r = 0; r < 4; r++) pk[r] = f2b(acc[mt][r] + bb[r]);  // no relu
        if (r15 < 8) *(u16x4*)(flat + (nb + r15) * 256 + o) = pk;
      }
    }
  }
}

// ---------------------------------------------------------------------------
// main v6-exact (R6, best measured 42.4 us): symmetric pipeline, wv&1
// stagger, one barrier/iter. R10 closed role-split: at 2 waves/SIMD the
// unified-reg budget is 256/wave; af_w[4][8] designs structurally spill.
// ---------------------------------------------------------------------------
#define NT 8  // tiles per block
__global__ __launch_bounds__(512, 2) void dense_edge_main(
    const u16* __restrict__ flat, const int* __restrict__ pidx,
    const int* __restrict__ cidx, const u16* __restrict__ w1s,
    const u16* __restrict__ w2s, const float* __restrict__ b1,
    const float* __restrict__ b2, const float* __restrict__ w3,
    const float* __restrict__ b3, float* __restrict__ out) {
  __shared__ u16 xxbuf[2][16384];    // [tile&1][cc(32)][n(64)][8]
  __shared__ u16 t1buf[2][16384];    // same layout
  __shared__ u16 pstage[2048];       // p-rows [cc(32)][row(8)][8]
  __shared__ u16 qstage[2][2048];    // q-rows, double-buffered by tile parity
  __shared__ float pbuf[2][8][2][64];// [tile&1][wave][o3][edge]

  const int t = threadIdx.x;
  const int wv = t >> 6;
  const int ln = t & 63;
  const int q4 = ln >> 4, r15 = ln & 15;
  const int blk = blockIdx.x;
  const int tile0 = blk * NT;
  const int b = tile0 >> 10;
  const int pt = (tile0 >> 5) & 31;
  const int qt0 = tile0 & 31;
  const int p0 = pt * 8;

  // both weight slices: 32 rows each of W1 and W2 (staged layout, 256B segs)
  bf16x8 w1f[2][8], w2f[2][8];
#pragma unroll
  for (int s = 0; s < 8; s++)
#pragma unroll
    for (int mt = 0; mt < 2; mt++) {
      const int off = ((s * 4 + q4) * 256 + wv * 32 + mt * 16 + r15) * 8;
      w1f[mt][s] = *(const bf16x8*)(w1s + off);
      w2f[mt][s] = *(const bf16x8*)(w2s + off);
    }

  // initial staging: waves 0-3 -> pstage, waves 4-7 -> qstage[0]
  const int slot4 = (wv & 3) * 64 + ln;
  const int srow = slot4 & 7, scc = slot4 >> 3;
  if (wv < 4) {
    const int pn = pidx[b * 256 + p0 + srow];
    gld_lds16(flat + pn * 256 + scc * 8, &pstage[slot4 * 8]);
  } else {
    const int qn = cidx[b * 256 + qt0 * 8 + srow];
    gld_lds16(flat + qn * 256 + scc * 8, &qstage[0][slot4 * 8]);
  }
  // preload q indices: tile 1 (prologue gld) and tile 2 (phase-0 gld)
  int qn_pro = 0, qn_cur = 0;
  if (wv >= 4) {
    qn_pro = cidx[b * 256 + (qt0 + 1) * 8 + srow];
    qn_cur = cidx[b * 256 + (qt0 + 2) * 8 + srow];
  }
  __syncthreads();

  const int prow = ln >> 3, qrow = ln & 7;

  // p-rows constant across tiles: hoist to registers (frees LDS path in XX)
  bf16x8 pa[4];
#pragma unroll
  for (int i = 0; i < 4; i++)
    pa[i] = *(const bf16x8*)(&pstage[((wv * 4 + i) * 8 + prow) * 8]);

  // ---- work items as lambdas (inlined twice for parity stagger) ----
  auto do_xx = [&](int jx) {
    const u16* qs = qstage[jx & 1];
    u16* xb = xxbuf[jx & 1];
#pragma unroll
    for (int i = 0; i < 4; i++) {
      const int cc = wv * 4 + i;
      bf16x8 av = pa[i];
      bf16x8 bv = *(const bf16x8*)(&qs[(cc * 8 + qrow) * 8]);
      bf16x8 ov;
#pragma unroll
      for (int jj = 0; jj < 8; jj++) {
        float d = b2f((u16)av[jj]) - b2f((u16)bv[jj]);
        ov[jj] = (short)f2b(d * d);
      }
      *(bf16x8*)(&xb[(cc * 64 + ln) * 8]) = ov;
    }
  };

  auto do_g1 = [&](int jg) {
    const u16* xb = xxbuf[jg & 1];
    f32x4 acc[2][4];
    {
      f32x4 zero = {0.f, 0.f, 0.f, 0.f};
#pragma unroll
      for (int mt = 0; mt < 2; mt++)
#pragma unroll
        for (int nt = 0; nt < 4; nt++) acc[mt][nt] = zero;
    }
    __builtin_amdgcn_s_setprio(1);
#pragma unroll
    for (int s = 0; s < 8; s++) {
      bf16x8 bfr[4];
#pragma unroll
      for (int nt = 0; nt < 4; nt++)
        bfr[nt] = *(const bf16x8*)(xb + ((s * 4 + q4) * 64 + nt * 16 + r15) * 8);
#pragma unroll
      for (int mt = 0; mt < 2; mt++)
#pragma unroll
        for (int nt = 0; nt < 4; nt++)
          acc[mt][nt] = __builtin_amdgcn_mfma_f32_16x16x32_bf16(w1f[mt][s], bfr[nt], acc[mt][nt], 0, 0, 0);
    }
    __builtin_amdgcn_s_setprio(0);
#pragma unroll
    for (int mt = 0; mt < 2; mt++) {
      const int o = wv * 32 + mt * 16 + q4 * 4;
      f32x4 bb = *(const f32x4*)(b1 + o);
#pragma unroll
      for (int nt = 0; nt < 4; nt++) {
        const int nn = nt * 16 + r15;
        u16x4 pk;
#pragma unroll
        for (int r = 0; r < 4; r++) {
          float v = fmaxf(acc[mt][nt][r] + bb[r], 0.f);
          pk[r] = f2b(v);
        }
        *(u16x4*)(&t1buf[jg & 1][((o >> 3) * 64 + nn) * 8 + (o & 7)]) = pk;
      }
    }
  };

  auto do_g2 = [&](int jg) {
    const u16* tb = t1buf[jg & 1];
    f32x4 acc[2][4];
    {
      f32x4 zero = {0.f, 0.f, 0.f, 0.f};
#pragma unroll
      for (int mt = 0; mt < 2; mt++)
#pragma unroll
        for (int nt = 0; nt < 4; nt++) acc[mt][nt] = zero;
    }
    __builtin_amdgcn_s_setprio(1);
#pragma unroll
    for (int s = 0; s < 8; s++) {
      bf16x8 bfr[4];
#pragma unroll
      for (int nt = 0; nt < 4; nt++)
        bfr[nt] = *(const bf16x8*)(tb + ((s * 4 + q4) * 64 + nt * 16 + r15) * 8);
#pragma unroll
      for (int mt = 0; mt < 2; mt++)
#pragma unroll
        for (int nt = 0; nt < 4; nt++)
          acc[mt][nt] = __builtin_amdgcn_mfma_f32_16x16x32_bf16(w2f[mt][s], bfr[nt], acc[mt][nt], 0, 0, 0);
    }
    __builtin_amdgcn_s_setprio(0);
    float part[2][4] = {{0.f, 0.f, 0.f, 0.f}, {0.f, 0.f, 0.f, 0.f}};
#pragma unroll
    for (int mt = 0; mt < 2; mt++) {
      const int o = wv * 32 + mt * 16 + q4 * 4;
      f32x4 bb = *(const f32x4*)(b2 + o);
      f32x4 w3a = *(const f32x4*)(w3 + o);
      f32x4 w3b = *(const f32x4*)(w3 + 256 + o);
#pragma unroll
      for (int nt = 0; nt < 4; nt++) {
#pragma unroll
        for (int r = 0; r < 4; r++) {
          float v = fmaxf(acc[mt][nt][r] + bb[r], 0.f);
          part[0][nt] += v * w3a[r];
          part[1][nt] += v * w3b[r];
        }
      }
    }
#pragma unroll
    for (int o3 = 0; o3 < 2; o3++)
#pragma unroll
      for (int nt = 0; nt < 4; nt++) {
        part[o3][nt] += __shfl_xor(part[o3][nt], 16, 64);
        part[o3][nt] += __shfl_xor(part[o3][nt], 32, 64);
      }
    if (q4 == 0) {
#pragma unroll
      for (int o3 = 0; o3 < 2; o3++)
#pragma unroll
        for (int nt = 0; nt < 4; nt++)
          pbuf[jg & 1][wv][o3][nt * 16 + r15] = part[o3][nt];
    }
  };

  // prologue: XX(0); issue q-gather for tile 1
  do_xx(0);
  if (wv >= 4) gld_lds16(flat + qn_pro * 256 + scc * 8, &qstage[1][slot4 * 8]);
  __syncthreads();

#pragma unroll 1
  for (int j = 0; j <= NT; j++) {
    // ---- early: out(j-2) global store (drains under this phase's compute)
    if (j >= 2 && t < 128) {
      const int jo = j - 2;
      const int o3 = t >> 6;
      const int n = t & 63;
      float v = b3[o3];
#pragma unroll
      for (int k = 0; k < 8; k++) v += pbuf[jo & 1][k][o3][n];
      out[((b * 2 + o3) * 256 + p0 + (n >> 3)) * 256 + (qt0 + jo) * 8 + (n & 7)] = v;
    }
    // ---- early: q-gather for tile j+2 (address already in reg)
    if (j < NT - 2 && wv >= 4) {
      gld_lds16(flat + qn_cur * 256 + scc * 8, &qstage[j & 1][slot4 * 8]);
      if (j < NT - 3) qn_cur = cidx[b * 256 + (qt0 + j + 3) * 8 + srow];
    }
    // ---- parity-staggered work ----
    if (wv & 1) {
      if (j < NT - 1) do_xx(j + 1);
      if (j > 0) do_g2(j - 1);
      if (j < NT) do_g1(j);
    } else {
      if (j < NT) do_g1(j);
      if (j > 0) do_g2(j - 1);
      if (j < NT - 1) do_xx(j + 1);
    }
    __syncthreads();
  }

  // epilogue: out(NT-1)
  if (t < 128) {
    const int jo = NT - 1;
    const int o3 = t >> 6;
    const int n = t & 63;
    float v = b3[o3];
#pragma unroll
    for (int k = 0; k < 8; k++) v += pbuf[jo & 1][k][o3][n];
    out[((b * 2 + o3) * 256 + p0 + (n >> 3)) * 256 + (qt0 + jo) * 8 + (n & 7)] = v;
  }
}

// ---------------------------------------------------------------------------
extern "C" void kernel_launch(void* const* d_in, const int* in_sizes, int n_in,
                              void* d_out, int out_size, void* d_ws, size_t ws_size,
                              hipStream_t stream) {
  (void)in_sizes; (void)n_in; (void)out_size; (void)ws_size;
  const float* x          = (const float*)d_in[0];
  const int*   pidx       = (const int*)d_in[1];
  const int*   cidx       = (const int*)d_in[2];
  const float* pre_w      = (const float*)d_in[3];
  const float* pre_b      = (const float*)d_in[4];
  const float* post_w     = (const float*)d_in[5];
  const float* post_b     = (const float*)d_in[6];
  const float* post_out_w = (const float*)d_in[7];
  const float* post_out_b = (const float*)d_in[8];
  float* out = (float*)d_out;

  u16* ws   = (u16*)d_ws;
  u16* w1s  = ws;              // staged bf16 W1 [s8][m][8]
  u16* w2s  = ws + 65536;      // staged bf16 W2
  u16* flat = ws + 131072;     // node features bf16 [2048][256]

  dense_edge_pre2<<<320, 256, 0, stream>>>(x, pre_w, pre_b, post_w, ws, flat);
  dense_edge_main<<<256, 512, 0, stream>>>(flat, pidx, cidx, w1s, w2s,
                                           post_b, post_b + 256,
                                           post_out_w, post_out_b, out);
}

// Round 12
// 117.691 us; speedup vs baseline: 1.1673x; 1.1673x over previous
//
#include <hip/hip_runtime.h>

typedef unsigned short u16;
typedef short bf16x8 __attribute__((ext_vector_type(8)));
typedef float f32x4 __attribute__((ext_vector_type(4)));
typedef u16 u16x4 __attribute__((ext_vector_type(4)));

__device__ __forceinline__ float b2f(u16 h) {
  unsigned u = ((unsigned)h) << 16;
  return __builtin_bit_cast(float, u);
}
// native RTNE f32->bf16; compiler pairs these into v_cvt_pk_bf16_f32
__device__ __forceinline__ u16 f2b(float f) {
  return __builtin_bit_cast(u16, (__bf16)f);
}
__device__ __forceinline__ void gld_lds16(const void* g, void* l) {
  __builtin_amdgcn_global_load_lds(
      (__attribute__((address_space(1))) void*)(g),
      (__attribute__((address_space(3))) void*)(l), 16, 0, 0);
}

// ---------------------------------------------------------------------------
// prep (R6-exact): blocks [0,160): fp32 weights -> bf16 STAGED
//   [layer][s8(32)][m(256)][8]; layers: 0,1 = post_w; 2,3,4 = pre_w
// blocks [160,416): x [2][256][1024] fp32 -> xt [2048][256] bf16 (transpose)
// ---------------------------------------------------------------------------
__global__ void dense_edge_prep(const float* __restrict__ x,
                                const float* __restrict__ pre_w,
                                const float* __restrict__ post_w,
                                u16* __restrict__ wb, u16* __restrict__ xt) {
  const int blk = blockIdx.x;
  const int t = threadIdx.x;
  if (blk < 160) {
    const int id = blk * 256 + t;      // 40960 slots of 8 elems
    const int layer = id >> 13;        // 0..4
    const int sid = id & 8191;
    const int m = sid >> 5;
    const int s8 = sid & 31;
    const float* src = (layer < 2) ? (post_w + layer * 65536)
                                   : (pre_w + (layer - 2) * 65536);
    u16* dst = wb + layer * 65536;
    f32x4 a = *(const f32x4*)(src + m * 256 + s8 * 8);
    f32x4 c = *(const f32x4*)(src + m * 256 + s8 * 8 + 4);
    bf16x8 o;
#pragma unroll
    for (int j = 0; j < 4; j++) o[j] = (short)f2b(a[j]);
#pragma unroll
    for (int j = 0; j < 4; j++) o[4 + j] = (short)f2b(c[j]);
    *(bf16x8*)(dst + (s8 * 256 + m) * 8) = o;
  } else {
    __shared__ float tile[32 * 65];
    const int xb = blk - 160;          // 2 b x 8 ctile x 16 hwtile = 256
    const int b = xb >> 7;
    const int ct = (xb >> 4) & 7;
    const int ht = xb & 15;
    const int c0 = ct * 32, hw0 = ht * 64;
#pragma unroll
    for (int rep = 0; rep < 8; rep++) {
      const int idx = rep * 256 + t;
      const int cl = idx >> 6, hl = idx & 63;
      tile[cl * 65 + hl] = x[(b * 256 + c0 + cl) * 1024 + hw0 + hl];
    }
    __syncthreads();
    const int hl = t >> 2, c8 = t & 3;
    bf16x8 o;
#pragma unroll
    for (int i = 0; i < 8; i++) o[i] = (short)f2b(tile[(c8 * 8 + i) * 65 + hl]);
    *(bf16x8*)(xt + (b * 1024 + hw0 + hl) * 256 + c0 + c8 * 8) = o;
  }
}

// ---------------------------------------------------------------------------
// pre (R6-exact): 3-layer 1x1-conv chain on 2048 nodes, bf16 MFMA.
// ---------------------------------------------------------------------------
__global__ __launch_bounds__(256, 2) void dense_edge_pre(
    const u16* __restrict__ xt, const u16* __restrict__ wpre,
    const float* __restrict__ preb, u16* __restrict__ flat) {
  __shared__ u16 feat[2][4096];  // [32 s8][16 n][8] each
  const int t = threadIdx.x;
  const int wv = t >> 6, ln = t & 63;
  const int nb = blockIdx.x * 16;
  const int q4 = ln >> 4, r15 = ln & 15;

#pragma unroll
  for (int i = 0; i < 2; i++) {
    const int slot = wv * 128 + i * 64 + ln;
    const int s8 = slot >> 4, nl = slot & 15;
    gld_lds16(xt + (nb + nl) * 256 + s8 * 8, &feat[0][slot * 8]);
  }
  __syncthreads();

#pragma unroll
  for (int l = 0; l < 3; l++) {
    const u16* wl = wpre + l * 65536;
    f32x4 acc[4];
    f32x4 zero = {0.f, 0.f, 0.f, 0.f};
#pragma unroll
    for (int mt = 0; mt < 4; mt++) acc[mt] = zero;
#pragma unroll
    for (int s = 0; s < 8; s++) {
      bf16x8 bv = *(const bf16x8*)(&feat[l & 1][((s * 4 + q4) * 16 + r15) * 8]);
#pragma unroll
      for (int mt = 0; mt < 4; mt++) {
        bf16x8 av = *(const bf16x8*)(wl + ((s * 4 + q4) * 256 + wv * 64 + mt * 16 + r15) * 8);
        acc[mt] = __builtin_amdgcn_mfma_f32_16x16x32_bf16(av, bv, acc[mt], 0, 0, 0);
      }
    }
    if (l < 2) {
#pragma unroll
      for (int mt = 0; mt < 4; mt++) {
        const int o = wv * 64 + mt * 16 + q4 * 4;
        f32x4 bb = *(const f32x4*)(preb + l * 256 + o);
        u16x4 pk;
#pragma unroll
        for (int r = 0; r < 4; r++) {
          float v = fmaxf(acc[mt][r] + bb[r], 0.f);
          pk[r] = f2b(v);
        }
        *(u16x4*)(&feat[(l + 1) & 1][((o >> 3) * 16 + r15) * 8 + (o & 7)]) = pk;
      }
      __syncthreads();
    } else {
#pragma unroll
      for (int mt = 0; mt < 4; mt++) {
        const int o = wv * 64 + mt * 16 + q4 * 4;
        f32x4 bb = *(const f32x4*)(preb + 512 + o);
        u16x4 pk;
#pragma unroll
        for (int r = 0; r < 4; r++) pk[r] = f2b(acc[mt][r] + bb[r]);  // no relu
        *(u16x4*)(flat + (nb + r15) * 256 + o) = pk;
      }
    }
  }
}

// ---------------------------------------------------------------------------
// main v9: ROLE-SPLIT mt=4/nt=2, 32-edge tiles (8p x 4q), 16 tiles/block.
// Waves 0-3: W1 (af[4][8]=128 regs, 64 rows each) -> G1 + XX-build.
// Waves 4-7: W2 -> G2 + W3 epilogue + out + q-gather.
// acc[4][2]=32 regs (NOT v8's acc[4][4]=64 -> that broke the 256-reg/wave
// budget, R10 law). Peak ~225 regs/wave -> no spill at 2 waves/SIMD.
// mt=4 doubles B-frag reuse: LDS ~170KB/tile (1.3k cyc) < MFMA 2.5k cyc;
// v6's co-critical LDS (4.5k cyc/iter) drops below the matrix pipe.
// wv%4 SIMD mapping: every SIMD hosts 1 G1-wave + 1 G2-wave each iter.
// ---------------------------------------------------------------------------
#define NTILE 16
__global__ __launch_bounds__(512, 2) void dense_edge_main(
    const u16* __restrict__ flat, const int* __restrict__ pidx,
    const int* __restrict__ cidx, const u16* __restrict__ w1s,
    const u16* __restrict__ w2s, const float* __restrict__ b1,
    const float* __restrict__ b2, const float* __restrict__ w3,
    const float* __restrict__ b3, float* __restrict__ out) {
  __shared__ u16 xxbuf[2][8192];    // [par][cc(32)][n(32)][8]  2x16 KB
  __shared__ u16 t1buf[2][8192];    // same layout              2x16 KB
  __shared__ u16 pstage[2048];      // [cc(32)][p(8)][8]        4 KB
  __shared__ u16 qstage[2][1024];   // [cc(32)][q(4)][8] dbuf   2x2 KB
  __shared__ float pbuf[2][4][2][32];// [par][cw][o3][n]        2 KB

  const int t = threadIdx.x;
  const int wv = t >> 6;
  const int ln = t & 63;
  const int q4 = ln >> 4, r15 = ln & 15;
  const bool prod = wv < 4;
  const int cw = wv & 3;
  const int blk = blockIdx.x;
  const int b = blk >> 7;            // 128 blocks per batch
  const int pt = (blk >> 2) & 31;
  const int qg = blk & 3;
  const int p0 = pt * 8;
  const int q0 = qg * 64;

  // role weights: 64 m-rows per wave (4 waves cover 256) from staged layout
  const u16* wsrc = prod ? w1s : w2s;
  bf16x8 af[4][8];
#pragma unroll
  for (int s = 0; s < 8; s++)
#pragma unroll
    for (int mt = 0; mt < 4; mt++)
      af[mt][s] = *(const bf16x8*)(wsrc + ((s * 4 + q4) * 256 + cw * 64 + mt * 16 + r15) * 8);

  // staging: producers -> pstage; waves 4,5 -> qstage[0] (tile 0);
  //          waves 6,7 -> qstage[1] (tile 1)
  if (prod) {
    const int slot = cw * 64 + ln;           // 0..255
    const int prow = slot & 7, cc = slot >> 3;
    const int pn = pidx[b * 256 + p0 + prow];
    gld_lds16(flat + pn * 256 + cc * 8, &pstage[slot * 8]);
  } else {
    const int half = (wv - 4) >> 1;          // 0 or 1 = tile parity buffer
    const int slot = ((wv - 4) & 1) * 64 + ln;  // 0..127
    const int cc = slot >> 2, qrow = slot & 3;
    const int qn = cidx[b * 256 + q0 + half * 4 + qrow];
    gld_lds16(flat + qn * 256 + cc * 8, &qstage[half][slot * 8]);
  }
  // gather lane constants + index preload for tile 2 (waves 6,7)
  const int gslot = (wv >= 6) ? (wv - 6) * 64 + ln : 0;
  int qn_cur = 0;
  if (wv >= 6) qn_cur = cidx[b * 256 + q0 + 8 + (gslot & 3)];
  __syncthreads();

  // producers: hoist p-row fragments (constant across all 16 tiles)
  const int nn32 = ln & 31;
  const int half32 = ln >> 5;
  bf16x8 pa[4];
  if (prod) {
#pragma unroll
    for (int i = 0; i < 4; i++) {
      const int cc = cw * 8 + half32 * 4 + i;
      pa[i] = *(const bf16x8*)(&pstage[((cc * 8 + (nn32 >> 2))) * 8]);
    }
  }

  // ---- producer: XX build (8 cc-chunks, 2 per lane-half x 4 iters) ----
  auto do_xx = [&](int jx) {
    const u16* qs = qstage[jx & 1];
    u16* xb = xxbuf[jx & 1];
#pragma unroll
    for (int i = 0; i < 4; i++) {
      const int cc = cw * 8 + half32 * 4 + i;
      bf16x8 av = pa[i];
      bf16x8 bv = *(const bf16x8*)(&qs[(cc * 4 + (nn32 & 3)) * 8]);
      bf16x8 ov;
#pragma unroll
      for (int jj = 0; jj < 8; jj++) {
        float d = b2f((u16)av[jj]) - b2f((u16)bv[jj]);
        ov[jj] = (short)f2b(d * d);
      }
      *(bf16x8*)(&xb[(cc * 32 + nn32) * 8]) = ov;
    }
  };

  // ---- producer: GEMM1 (64 MFMA) + relu/b1 pack -> t1buf ----
  auto do_g1 = [&](int jg) {
    const u16* xb = xxbuf[jg & 1];
    f32x4 acc[4][2];
    {
      f32x4 zero = {0.f, 0.f, 0.f, 0.f};
#pragma unroll
      for (int mt = 0; mt < 4; mt++)
#pragma unroll
        for (int nt = 0; nt < 2; nt++) acc[mt][nt] = zero;
    }
    __builtin_amdgcn_s_setprio(1);
#pragma unroll
    for (int s = 0; s < 8; s++) {
      bf16x8 bfr[2];
#pragma unroll
      for (int nt = 0; nt < 2; nt++)
        bfr[nt] = *(const bf16x8*)(xb + ((s * 4 + q4) * 32 + nt * 16 + r15) * 8);
#pragma unroll
      for (int mt = 0; mt < 4; mt++)
#pragma unroll
        for (int nt = 0; nt < 2; nt++)
          acc[mt][nt] = __builtin_amdgcn_mfma_f32_16x16x32_bf16(af[mt][s], bfr[nt], acc[mt][nt], 0, 0, 0);
    }
    __builtin_amdgcn_s_setprio(0);
#pragma unroll
    for (int mt = 0; mt < 4; mt++) {
      const int o = cw * 64 + mt * 16 + q4 * 4;
      f32x4 bb = *(const f32x4*)(b1 + o);
#pragma unroll
      for (int nt = 0; nt < 2; nt++) {
        const int n = nt * 16 + r15;
        u16x4 pk;
#pragma unroll
        for (int r = 0; r < 4; r++) {
          float v = fmaxf(acc[mt][nt][r] + bb[r], 0.f);
          pk[r] = f2b(v);
        }
        *(u16x4*)(&t1buf[jg & 1][((o >> 3) * 32 + n) * 8 + (o & 7)]) = pk;
      }
    }
  };

  // ---- consumer: GEMM2 (64 MFMA) + W3 epilogue -> pbuf ----
  auto do_g2 = [&](int jg) {
    const u16* tb = t1buf[jg & 1];
    f32x4 acc[4][2];
    {
      f32x4 zero = {0.f, 0.f, 0.f, 0.f};
#pragma unroll
      for (int mt = 0; mt < 4; mt++)
#pragma unroll
        for (int nt = 0; nt < 2; nt++) acc[mt][nt] = zero;
    }
    __builtin_amdgcn_s_setprio(1);
#pragma unroll
    for (int s = 0; s < 8; s++) {
      bf16x8 bfr[2];
#pragma unroll
      for (int nt = 0; nt < 2; nt++)
        bfr[nt] = *(const bf16x8*)(tb + ((s * 4 + q4) * 32 + nt * 16 + r15) * 8);
#pragma unroll
      for (int mt = 0; mt < 4; mt++)
#pragma unroll
        for (int nt = 0; nt < 2; nt++)
          acc[mt][nt] = __builtin_amdgcn_mfma_f32_16x16x32_bf16(af[mt][s], bfr[nt], acc[mt][nt], 0, 0, 0);
    }
    __builtin_amdgcn_s_setprio(0);
    float part[2][2] = {{0.f, 0.f}, {0.f, 0.f}};
#pragma unroll
    for (int mt = 0; mt < 4; mt++) {
      const int o = cw * 64 + mt * 16 + q4 * 4;
      f32x4 bb = *(const f32x4*)(b2 + o);
      f32x4 w3a = *(const f32x4*)(w3 + o);
      f32x4 w3b = *(const f32x4*)(w3 + 256 + o);
#pragma unroll
      for (int nt = 0; nt < 2; nt++) {
#pragma unroll
        for (int r = 0; r < 4; r++) {
          float v = fmaxf(acc[mt][nt][r] + bb[r], 0.f);
          part[0][nt] += v * w3a[r];
          part[1][nt] += v * w3b[r];
        }
      }
    }
#pragma unroll
    for (int o3 = 0; o3 < 2; o3++)
#pragma unroll
      for (int nt = 0; nt < 2; nt++) {
        part[o3][nt] += __shfl_xor(part[o3][nt], 16, 64);
        part[o3][nt] += __shfl_xor(part[o3][nt], 32, 64);
      }
    if (q4 == 0) {
#pragma unroll
      for (int o3 = 0; o3 < 2; o3++)
#pragma unroll
        for (int nt = 0; nt < 2; nt++)
          pbuf[jg & 1][cw][o3][nt * 16 + r15] = part[o3][nt];
    }
  };

  // ---- consumer wave 4: output store for tile jo ----
  auto do_out = [&](int jo) {
    const int o3 = ln >> 5, n = ln & 31;
    float v = b3[o3];
#pragma unroll
    for (int k = 0; k < 4; k++) v += pbuf[jo & 1][k][o3][n];
    out[((b * 2 + o3) * 256 + p0 + (n >> 2)) * 256 + q0 + jo * 4 + (n & 3)] = v;
  };

  // prologue: producers build XX(0)
  if (prod) do_xx(0);
  __syncthreads();

#pragma unroll 1
  for (int j = 0; j <= NTILE; j++) {
    if (prod) {
      if (j < NTILE) do_g1(j);
      if (j < NTILE - 1) do_xx(j + 1);
    } else {
      if (wv == 4 && j >= 2) do_out(j - 2);
      if (wv >= 6 && j < NTILE - 2) {
        gld_lds16(flat + qn_cur * 256 + (gslot >> 2) * 8,
                  &qstage[j & 1][gslot * 8]);
        if (j < NTILE - 3)
          qn_cur = cidx[b * 256 + q0 + (j + 3) * 4 + (gslot & 3)];
      }
      if (j >= 1) do_g2(j - 1);
    }
    __syncthreads();
  }

  // epilogue: out(NTILE-1)
  if (wv == 4) do_out(NTILE - 1);
}

// ---------------------------------------------------------------------------
extern "C" void kernel_launch(void* const* d_in, const int* in_sizes, int n_in,
                              void* d_out, int out_size, void* d_ws, size_t ws_size,
                              hipStream_t stream) {
  (void)in_sizes; (void)n_in; (void)out_size; (void)ws_size;
  const float* x          = (const float*)d_in[0];
  const int*   pidx       = (const int*)d_in[1];
  const int*   cidx       = (const int*)d_in[2];
  const float* pre_w      = (const float*)d_in[3];
  const float* pre_b      = (const float*)d_in[4];
  const float* post_w     = (const float*)d_in[5];
  const float* post_b     = (const float*)d_in[6];
  const float* post_out_w = (const float*)d_in[7];
  const float* post_out_b = (const float*)d_in[8];
  float* out = (float*)d_out;

  u16* ws   = (u16*)d_ws;
  u16* wb   = ws;              // staged bf16 weights: w1,w2,pre0,pre1,pre2
  u16* w1s  = wb;
  u16* w2s  = wb + 65536;
  u16* wpre = wb + 131072;
  u16* xt   = ws + 327680;     // x_t bf16 [2048][256]
  u16* flat = ws + 851968;     // node features bf16 [2048][256]

  dense_edge_prep<<<416, 256, 0, stream>>>(x, pre_w, post_w, wb, xt);
  dense_edge_pre<<<128, 256, 0, stream>>>(xt, wpre, pre_b, flat);
  dense_edge_main<<<256, 512, 0, stream>>>(flat, pidx, cidx, w1s, w2s,
                                           post_b, post_b + 256,
                                           post_out_w, post_out_b, out);
}

// Round 13
// 117.267 us; speedup vs baseline: 1.1715x; 1.0036x over previous
//
#include <hip/hip_runtime.h>

typedef unsigned short u16;
typedef short bf16x8 __attribute__((ext_vector_type(8)));
typedef float f32x4 __attribute__((ext_vector_type(4)));
typedef u16 u16x4 __attribute__((ext_vector_type(4)));

__device__ __forceinline__ float b2f(u16 h) {
  unsigned u = ((unsigned)h) << 16;
  return __builtin_bit_cast(float, u);
}
// native RTNE f32->bf16; compiler pairs these into v_cvt_pk_bf16_f32
__device__ __forceinline__ u16 f2b(float f) {
  return __builtin_bit_cast(u16, (__bf16)f);
}
__device__ __forceinline__ void gld_lds16(const void* g, void* l) {
  __builtin_amdgcn_global_load_lds(
      (__attribute__((address_space(1))) void*)(g),
      (__attribute__((address_space(3))) void*)(l), 16, 0, 0);
}

// ---------------------------------------------------------------------------
// prep (R6-exact): blocks [0,160): fp32 weights -> bf16 STAGED
//   [layer][s8(32)][m(256)][8]; layers: 0,1 = post_w; 2,3,4 = pre_w
// blocks [160,416): x [2][256][1024] fp32 -> xt [2048][256] bf16 (transpose)
// ---------------------------------------------------------------------------
__global__ void dense_edge_prep(const float* __restrict__ x,
                                const float* __restrict__ pre_w,
                                const float* __restrict__ post_w,
                                u16* __restrict__ wb, u16* __restrict__ xt) {
  const int blk = blockIdx.x;
  const int t = threadIdx.x;
  if (blk < 160) {
    const int id = blk * 256 + t;      // 40960 slots of 8 elems
    const int layer = id >> 13;        // 0..4
    const int sid = id & 8191;
    const int m = sid >> 5;
    const int s8 = sid & 31;
    const float* src = (layer < 2) ? (post_w + layer * 65536)
                                   : (pre_w + (layer - 2) * 65536);
    u16* dst = wb + layer * 65536;
    f32x4 a = *(const f32x4*)(src + m * 256 + s8 * 8);
    f32x4 c = *(const f32x4*)(src + m * 256 + s8 * 8 + 4);
    bf16x8 o;
#pragma unroll
    for (int j = 0; j < 4; j++) o[j] = (short)f2b(a[j]);
#pragma unroll
    for (int j = 0; j < 4; j++) o[4 + j] = (short)f2b(c[j]);
    *(bf16x8*)(dst + (s8 * 256 + m) * 8) = o;
  } else {
    __shared__ float tile[32 * 65];
    const int xb = blk - 160;          // 2 b x 8 ctile x 16 hwtile = 256
    const int b = xb >> 7;
    const int ct = (xb >> 4) & 7;
    const int ht = xb & 15;
    const int c0 = ct * 32, hw0 = ht * 64;
#pragma unroll
    for (int rep = 0; rep < 8; rep++) {
      const int idx = rep * 256 + t;
      const int cl = idx >> 6, hl = idx & 63;
      tile[cl * 65 + hl] = x[(b * 256 + c0 + cl) * 1024 + hw0 + hl];
    }
    __syncthreads();
    const int hl = t >> 2, c8 = t & 3;
    bf16x8 o;
#pragma unroll
    for (int i = 0; i < 8; i++) o[i] = (short)f2b(tile[(c8 * 8 + i) * 65 + hl]);
    *(bf16x8*)(xt + (b * 1024 + hw0 + hl) * 256 + c0 + c8 * 8) = o;
  }
}

// ---------------------------------------------------------------------------
// pre (R6-exact): 3-layer 1x1-conv chain on 2048 nodes, bf16 MFMA.
// ---------------------------------------------------------------------------
__global__ __launch_bounds__(256, 2) void dense_edge_pre(
    const u16* __restrict__ xt, const u16* __restrict__ wpre,
    const float* __restrict__ preb, u16* __restrict__ flat) {
  __shared__ u16 feat[2][4096];  // [32 s8][16 n][8] each
  const int t = threadIdx.x;
  const int wv = t >> 6, ln = t & 63;
  const int nb = blockIdx.x * 16;
  const int q4 = ln >> 4, r15 = ln & 15;

#pragma unroll
  for (int i = 0; i < 2; i++) {
    const int slot = wv * 128 + i * 64 + ln;
    const int s8 = slot >> 4, nl = slot & 15;
    gld_lds16(xt + (nb + nl) * 256 + s8 * 8, &feat[0][slot * 8]);
  }
  __syncthreads();

#pragma unroll
  for (int l = 0; l < 3; l++) {
    const u16* wl = wpre + l * 65536;
    f32x4 acc[4];
    f32x4 zero = {0.f, 0.f, 0.f, 0.f};
#pragma unroll
    for (int mt = 0; mt < 4; mt++) acc[mt] = zero;
#pragma unroll
    for (int s = 0; s < 8; s++) {
      bf16x8 bv = *(const bf16x8*)(&feat[l & 1][((s * 4 + q4) * 16 + r15) * 8]);
#pragma unroll
      for (int mt = 0; mt < 4; mt++) {
        bf16x8 av = *(const bf16x8*)(wl + ((s * 4 + q4) * 256 + wv * 64 + mt * 16 + r15) * 8);
        acc[mt] = __builtin_amdgcn_mfma_f32_16x16x32_bf16(av, bv, acc[mt], 0, 0, 0);
      }
    }
    if (l < 2) {
#pragma unroll
      for (int mt = 0; mt < 4; mt++) {
        const int o = wv * 64 + mt * 16 + q4 * 4;
        f32x4 bb = *(const f32x4*)(preb + l * 256 + o);
        u16x4 pk;
#pragma unroll
        for (int r = 0; r < 4; r++) {
          float v = fmaxf(acc[mt][r] + bb[r], 0.f);
          pk[r] = f2b(v);
        }
        *(u16x4*)(&feat[(l + 1) & 1][((o >> 3) * 16 + r15) * 8 + (o & 7)]) = pk;
      }
      __syncthreads();
    } else {
#pragma unroll
      for (int mt = 0; mt < 4; mt++) {
        const int o = wv * 64 + mt * 16 + q4 * 4;
        f32x4 bb = *(const f32x4*)(preb + 512 + o);
        u16x4 pk;
#pragma unroll
        for (int r = 0; r < 4; r++) pk[r] = f2b(acc[mt][r] + bb[r]);  // no relu
        *(u16x4*)(flat + (nb + r15) * 256 + o) = pk;
      }
    }
  }
}

// ---------------------------------------------------------------------------
// main v10 = v9 + XX-build INTERLEAVED into G1's MFMA s-loop.
// The XX chunks (tile j+1) have zero data dependence on G1(j)'s accumulators
// -> the wave issues XX VALU/LDS into the gaps while its MFMAs occupy the
// matrix pipe (separate pipes). Tests the "serialized VALU phases" theory
// for the 42-us plateau (7 structural variants, all 42+-1).
// ---------------------------------------------------------------------------
#define NTILE 16
__global__ __launch_bounds__(512, 2) void dense_edge_main(
    const u16* __restrict__ flat, const int* __restrict__ pidx,
    const int* __restrict__ cidx, const u16* __restrict__ w1s,
    const u16* __restrict__ w2s, const float* __restrict__ b1,
    const float* __restrict__ b2, const float* __restrict__ w3,
    const float* __restrict__ b3, float* __restrict__ out) {
  __shared__ u16 xxbuf[2][8192];    // [par][cc(32)][n(32)][8]  2x16 KB
  __shared__ u16 t1buf[2][8192];    // same layout              2x16 KB
  __shared__ u16 pstage[2048];      // [cc(32)][p(8)][8]        4 KB
  __shared__ u16 qstage[2][1024];   // [cc(32)][q(4)][8] dbuf   2x2 KB
  __shared__ float pbuf[2][4][2][32];// [par][cw][o3][n]        2 KB

  const int t = threadIdx.x;
  const int wv = t >> 6;
  const int ln = t & 63;
  const int q4 = ln >> 4, r15 = ln & 15;
  const bool prod = wv < 4;
  const int cw = wv & 3;
  const int blk = blockIdx.x;
  const int b = blk >> 7;            // 128 blocks per batch
  const int pt = (blk >> 2) & 31;
  const int qg = blk & 3;
  const int p0 = pt * 8;
  const int q0 = qg * 64;

  // role weights: 64 m-rows per wave (4 waves cover 256) from staged layout
  const u16* wsrc = prod ? w1s : w2s;
  bf16x8 af[4][8];
#pragma unroll
  for (int s = 0; s < 8; s++)
#pragma unroll
    for (int mt = 0; mt < 4; mt++)
      af[mt][s] = *(const bf16x8*)(wsrc + ((s * 4 + q4) * 256 + cw * 64 + mt * 16 + r15) * 8);

  // staging: producers -> pstage; waves 4,5 -> qstage[0] (tile 0);
  //          waves 6,7 -> qstage[1] (tile 1)
  if (prod) {
    const int slot = cw * 64 + ln;           // 0..255
    const int prow = slot & 7, cc = slot >> 3;
    const int pn = pidx[b * 256 + p0 + prow];
    gld_lds16(flat + pn * 256 + cc * 8, &pstage[slot * 8]);
  } else {
    const int half = (wv - 4) >> 1;          // 0 or 1 = tile parity buffer
    const int slot = ((wv - 4) & 1) * 64 + ln;  // 0..127
    const int cc = slot >> 2, qrow = slot & 3;
    const int qn = cidx[b * 256 + q0 + half * 4 + qrow];
    gld_lds16(flat + qn * 256 + cc * 8, &qstage[half][slot * 8]);
  }
  // gather lane constants + index preload for tile 2 (waves 6,7)
  const int gslot = (wv >= 6) ? (wv - 6) * 64 + ln : 0;
  int qn_cur = 0;
  if (wv >= 6) qn_cur = cidx[b * 256 + q0 + 8 + (gslot & 3)];
  __syncthreads();

  // producers: hoist p-row fragments (constant across all 16 tiles)
  const int nn32 = ln & 31;
  const int half32 = ln >> 5;
  bf16x8 pa[4];
  if (prod) {
#pragma unroll
    for (int i = 0; i < 4; i++) {
      const int cc = cw * 8 + half32 * 4 + i;
      pa[i] = *(const bf16x8*)(&pstage[((cc * 8 + (nn32 >> 2))) * 8]);
    }
  }

  // ---- producer: XX build (standalone, used in prologue only) ----
  auto do_xx = [&](int jx) {
    const u16* qs = qstage[jx & 1];
    u16* xb = xxbuf[jx & 1];
#pragma unroll
    for (int i = 0; i < 4; i++) {
      const int cc = cw * 8 + half32 * 4 + i;
      bf16x8 av = pa[i];
      bf16x8 bv = *(const bf16x8*)(&qs[(cc * 4 + (nn32 & 3)) * 8]);
      bf16x8 ov;
#pragma unroll
      for (int jj = 0; jj < 8; jj++) {
        float d = b2f((u16)av[jj]) - b2f((u16)bv[jj]);
        ov[jj] = (short)f2b(d * d);
      }
      *(bf16x8*)(&xb[(cc * 32 + nn32) * 8]) = ov;
    }
  };

  // ---- producer: GEMM1(jg) with XX-build(jx) interleaved into the s-loop.
  // XX chunk i issued after s-iter i (i<4): its VALU/ds ops fill the wave's
  // issue slots while MFMAs of iters s..s+1 occupy the matrix pipe.
  auto do_g1x = [&](int jg, int jx, bool doxx) {
    const u16* xb = xxbuf[jg & 1];
    const u16* qs = qstage[jx & 1];
    u16* xw = xxbuf[jx & 1];
    f32x4 acc[4][2];
    {
      f32x4 zero = {0.f, 0.f, 0.f, 0.f};
#pragma unroll
      for (int mt = 0; mt < 4; mt++)
#pragma unroll
        for (int nt = 0; nt < 2; nt++) acc[mt][nt] = zero;
    }
    __builtin_amdgcn_s_setprio(1);
#pragma unroll
    for (int s = 0; s < 8; s++) {
      bf16x8 bfr[2];
#pragma unroll
      for (int nt = 0; nt < 2; nt++)
        bfr[nt] = *(const bf16x8*)(xb + ((s * 4 + q4) * 32 + nt * 16 + r15) * 8);
#pragma unroll
      for (int mt = 0; mt < 4; mt++)
#pragma unroll
        for (int nt = 0; nt < 2; nt++)
          acc[mt][nt] = __builtin_amdgcn_mfma_f32_16x16x32_bf16(af[mt][s], bfr[nt], acc[mt][nt], 0, 0, 0);
      if (doxx && s < 4) {
        const int cc = cw * 8 + half32 * 4 + s;
        bf16x8 av = pa[s];
        bf16x8 bv = *(const bf16x8*)(&qs[(cc * 4 + (nn32 & 3)) * 8]);
        bf16x8 ov;
#pragma unroll
        for (int jj = 0; jj < 8; jj++) {
          float d = b2f((u16)av[jj]) - b2f((u16)bv[jj]);
          ov[jj] = (short)f2b(d * d);
        }
        *(bf16x8*)(&xw[(cc * 32 + nn32) * 8]) = ov;
      }
    }
    __builtin_amdgcn_s_setprio(0);
#pragma unroll
    for (int mt = 0; mt < 4; mt++) {
      const int o = cw * 64 + mt * 16 + q4 * 4;
      f32x4 bb = *(const f32x4*)(b1 + o);
#pragma unroll
      for (int nt = 0; nt < 2; nt++) {
        const int n = nt * 16 + r15;
        u16x4 pk;
#pragma unroll
        for (int r = 0; r < 4; r++) {
          float v = fmaxf(acc[mt][nt][r] + bb[r], 0.f);
          pk[r] = f2b(v);
        }
        *(u16x4*)(&t1buf[jg & 1][((o >> 3) * 32 + n) * 8 + (o & 7)]) = pk;
      }
    }
  };

  // ---- consumer: GEMM2 (64 MFMA) + W3 epilogue -> pbuf ----
  auto do_g2 = [&](int jg) {
    const u16* tb = t1buf[jg & 1];
    f32x4 acc[4][2];
    {
      f32x4 zero = {0.f, 0.f, 0.f, 0.f};
#pragma unroll
      for (int mt = 0; mt < 4; mt++)
#pragma unroll
        for (int nt = 0; nt < 2; nt++) acc[mt][nt] = zero;
    }
    __builtin_amdgcn_s_setprio(1);
#pragma unroll
    for (int s = 0; s < 8; s++) {
      bf16x8 bfr[2];
#pragma unroll
      for (int nt = 0; nt < 2; nt++)
        bfr[nt] = *(const bf16x8*)(tb + ((s * 4 + q4) * 32 + nt * 16 + r15) * 8);
#pragma unroll
      for (int mt = 0; mt < 4; mt++)
#pragma unroll
        for (int nt = 0; nt < 2; nt++)
          acc[mt][nt] = __builtin_amdgcn_mfma_f32_16x16x32_bf16(af[mt][s], bfr[nt], acc[mt][nt], 0, 0, 0);
    }
    __builtin_amdgcn_s_setprio(0);
    float part[2][2] = {{0.f, 0.f}, {0.f, 0.f}};
#pragma unroll
    for (int mt = 0; mt < 4; mt++) {
      const int o = cw * 64 + mt * 16 + q4 * 4;
      f32x4 bb = *(const f32x4*)(b2 + o);
      f32x4 w3a = *(const f32x4*)(w3 + o);
      f32x4 w3b = *(const f32x4*)(w3 + 256 + o);
#pragma unroll
      for (int nt = 0; nt < 2; nt++) {
#pragma unroll
        for (int r = 0; r < 4; r++) {
          float v = fmaxf(acc[mt][nt][r] + bb[r], 0.f);
          part[0][nt] += v * w3a[r];
          part[1][nt] += v * w3b[r];
        }
      }
    }
#pragma unroll
    for (int o3 = 0; o3 < 2; o3++)
#pragma unroll
      for (int nt = 0; nt < 2; nt++) {
        part[o3][nt] += __shfl_xor(part[o3][nt], 16, 64);
        part[o3][nt] += __shfl_xor(part[o3][nt], 32, 64);
      }
    if (q4 == 0) {
#pragma unroll
      for (int o3 = 0; o3 < 2; o3++)
#pragma unroll
        for (int nt = 0; nt < 2; nt++)
          pbuf[jg & 1][cw][o3][nt * 16 + r15] = part[o3][nt];
    }
  };

  // ---- consumer wave 4: output store for tile jo ----
  auto do_out = [&](int jo) {
    const int o3 = ln >> 5, n = ln & 31;
    float v = b3[o3];
#pragma unroll
    for (int k = 0; k < 4; k++) v += pbuf[jo & 1][k][o3][n];
    out[((b * 2 + o3) * 256 + p0 + (n >> 2)) * 256 + q0 + jo * 4 + (n & 3)] = v;
  };

  // prologue: producers build XX(0)
  if (prod) do_xx(0);
  __syncthreads();

#pragma unroll 1
  for (int j = 0; j <= NTILE; j++) {
    if (prod) {
      if (j < NTILE) do_g1x(j, j + 1, j < NTILE - 1);
    } else {
      if (wv == 4 && j >= 2) do_out(j - 2);
      if (wv >= 6 && j < NTILE - 2) {
        gld_lds16(flat + qn_cur * 256 + (gslot >> 2) * 8,
                  &qstage[j & 1][gslot * 8]);
        if (j < NTILE - 3)
          qn_cur = cidx[b * 256 + q0 + (j + 3) * 4 + (gslot & 3)];
      }
      if (j >= 1) do_g2(j - 1);
    }
    __syncthreads();
  }

  // epilogue: out(NTILE-1)
  if (wv == 4) do_out(NTILE - 1);
}

// ---------------------------------------------------------------------------
extern "C" void kernel_launch(void* const* d_in, const int* in_sizes, int n_in,
                              void* d_out, int out_size, void* d_ws, size_t ws_size,
                              hipStream_t stream) {
  (void)in_sizes; (void)n_in; (void)out_size; (void)ws_size;
  const float* x          = (const float*)d_in[0];
  const int*   pidx       = (const int*)d_in[1];
  const int*   cidx       = (const int*)d_in[2];
  const float* pre_w      = (const float*)d_in[3];
  const float* pre_b      = (const float*)d_in[4];
  const float* post_w     = (const float*)d_in[5];
  const float* post_b     = (const float*)d_in[6];
  const float* post_out_w = (const float*)d_in[7];
  const float* post_out_b = (const float*)d_in[8];
  float* out = (float*)d_out;

  u16* ws   = (u16*)d_ws;
  u16* wb   = ws;              // staged bf16 weights: w1,w2,pre0,pre1,pre2
  u16* w1s  = wb;
  u16* w2s  = wb + 65536;
  u16* wpre = wb + 131072;
  u16* xt   = ws + 327680;     // x_t bf16 [2048][256]
  u16* flat = ws + 851968;     // node features bf16 [2048][256]

  dense_edge_prep<<<416, 256, 0, stream>>>(x, pre_w, post_w, wb, xt);
  dense_edge_pre<<<128, 256, 0, stream>>>(xt, wpre, pre_b, flat);
  dense_edge_main<<<256, 512, 0, stream>>>(flat, pidx, cidx, w1s, w2s,
                                           post_b, post_b + 256,
                                           post_out_w, post_out_b, out);
}